// Round 7
// baseline (421.904 us; speedup 1.0000x reference)
//
#include <hip/hip_runtime.h>

// FFT long conv: out[b,d,l] = (1/16384^2 forward-norm pair) * linear conv of x,f, masked.
// One workgroup per (b,d) channel; 3 complex FFTs (2 fwd + 1 packed inverse).
//
// R8: single 64 KB LDS buffer -> 2 blocks/CU (barrier-stall hiding).
//  * R7 post-mortem: DPP 5-stage passes REVERTED (VALUBusy 57->71%, conflicts 7.3e6->
//    1.74e7, dur +26us). Back to R6's verified pass maps + swz. Kept only the reg
//    first-pass (same staging write pattern as R6 = known conflict profile).
//  * Pack algebra: G's even bins depend ONLY on We, odd bins ONLY on Wo (see R6 code:
//    even cluster reads A only, odd cluster reads B only). So the branches run
//    SEQUENTIALLY in ONE 64KB buffer: odd FFT -> G-odd into 4 float2 REGISTERS ->
//    reload x,f (L3-hot) -> even FFT same buffer -> G-even -> write all G -> inverse.
//  * 64KB LDS + ~60 VGPR -> 2 blocks/CU co-resident: one block's barrier stalls hide
//    under the other's compute (R6 measured 44% occupancy = 1 block/CU, VALU idle 43%).
//  * Godd[4] (8 VGPRs) deliberately crosses the even-FFT barriers -- the one exception
//    to the R5 spill rule; WRITE_SIZE==65536KB exactly is the no-spill tripwire.
//
// positions arrives as int32 from the harness (int64 in the npz) - keep const int*.

#define N_FFT 8192
#define NT    1024
#define NPT   8
#define PI_F  3.14159265358979323846f
#define RS2   0.70710678118654752440f

__device__ __forceinline__ float2 cmul(float2 a, float2 b) {
    return make_float2(a.x * b.x - a.y * b.y, a.x * b.y + a.y * b.x);
}
__device__ __forceinline__ float2 cadd(float2 a, float2 b) { return make_float2(a.x + b.x, a.y + b.y); }
__device__ __forceinline__ float2 csub(float2 a, float2 b) { return make_float2(a.x - b.x, a.y - b.y); }
__device__ __forceinline__ float2 mneg_i(float2 a) { return make_float2(a.y, -a.x); }  // a * (-i)
__device__ __forceinline__ float2 mpos_i(float2 a) { return make_float2(-a.y, a.x); }  // a * (+i)

__device__ __forceinline__ int rev13(int v) { return (int)(__brev((unsigned)v) >> 19); }
// LDS bank swizzle: XOR bits 1..3 with bits 4..6 (float2 units). Bijective within [0,8192).
__device__ __forceinline__ int swz(int i) { return i ^ (((i >> 4) & 7) << 1); }

// Pass ownership: thread t owns elements base + (k<<B), k=0..7 (R6, verified).
template <int B>
__device__ __forceinline__ int pass_base(int t) {
    const int lo   = t & ((1 << B) - 1);
    const int hi   = t >> B;
    const int base = (hi << (B + 3)) | lo;
    if constexpr (B == 4) return base;
    else                  return base ^ (((base >> 4) & 7) << 1);
}
template <int B>
__device__ __forceinline__ int pass_addr(int sb, int k) {
    if constexpr (B >= 7)      return sb + (k << B);
    else if constexpr (B == 4) return (sb ^ (k << 1)) + (k << 4);
    else                       return sb ^ (k << 1);
}

// ---- register-only 3-stage DIF core (stages b+2,b+1,b on r[8]); R7-verified math ----
__device__ __forceinline__ void fwd_core3(float2 r[8], float2 T1) {
    const float2 T2  = cmul(T1, T1);
    const float2 T4  = cmul(T2, T2);
    const float2 T1b = cmul(T1, make_float2(RS2, -RS2));       // T1 * e^{-i pi/4}
#pragma unroll
    for (int k = 0; k < 4; ++k) {
        float2 u = r[k], v = r[k + 4];
        r[k] = cadd(u, v);
        float2 d  = csub(u, v);
        float2 tw = (k == 0) ? T1 : (k == 1) ? T1b : (k == 2) ? mneg_i(T1) : mneg_i(T1b);
        r[k + 4] = cmul(d, tw);
    }
#pragma unroll
    for (int k0 = 0; k0 < 8; k0 += 4) {
#pragma unroll
        for (int kk = 0; kk < 2; ++kk) {
            const int k = k0 + kk;
            float2 u = r[k], v = r[k + 2];
            r[k] = cadd(u, v);
            r[k + 2] = cmul(csub(u, v), kk ? mneg_i(T2) : T2);
        }
    }
#pragma unroll
    for (int k = 0; k < 8; k += 2) {
        float2 u = r[k], v = r[k + 1];
        r[k] = cadd(u, v);
        r[k + 1] = cmul(csub(u, v), T4);
    }
}

// ---- forward DIF merged LDS pass (R6 verbatim, verified) ----
template <int B, bool LAST>
__device__ __forceinline__ void fwd_pass(float2* a, int t) {
    const int h  = 1 << B;
    const int lo = t & (h - 1);
    const int sb = pass_base<B>(t);
    float2 r[8];
#pragma unroll
    for (int k = 0; k < 8; ++k) r[k] = a[pass_addr<B>(sb, k)];

    float sn, cs;
    __sincosf(-PI_F * (float)lo / (float)(4 * h), &sn, &cs);
    fwd_core3(r, make_float2(cs, sn));

    if (LAST) {  // stage 0 (half=1, twiddle 1): partner is lane t^1, same k
        const float sgn = (t & 1) ? -1.0f : 1.0f;
#pragma unroll
        for (int k = 0; k < 8; ++k) {
            float ox = __shfl_xor(r[k].x, 1);
            float oy = __shfl_xor(r[k].y, 1);
            r[k].x = ox + sgn * r[k].x;
            r[k].y = oy + sgn * r[k].y;
        }
    }
#pragma unroll
    for (int k = 0; k < 8; ++k) a[pass_addr<B>(sb, k)] = r[k];
}

// ---- inverse DIT merged LDS pass (R6 verbatim, verified) ----
template <int B, bool FIRST, bool STORE>
__device__ __forceinline__ void inv_pass(float2* a, int t, float2 r[8]) {
    const int h  = 1 << B;
    const int lo = t & (h - 1);
    const int sb = pass_base<B>(t);
#pragma unroll
    for (int k = 0; k < 8; ++k) r[k] = a[pass_addr<B>(sb, k)];

    if (FIRST) {
        const float sgn = (t & 1) ? -1.0f : 1.0f;
#pragma unroll
        for (int k = 0; k < 8; ++k) {
            float ox = __shfl_xor(r[k].x, 1);
            float oy = __shfl_xor(r[k].y, 1);
            r[k].x = ox + sgn * r[k].x;
            r[k].y = oy + sgn * r[k].y;
        }
    }
    float sn, cs;
    __sincosf(PI_F * (float)lo / (float)(4 * h), &sn, &cs);
    const float2 U1  = make_float2(cs, sn);
    const float2 U2  = cmul(U1, U1);
    const float2 U4  = cmul(U2, U2);
    const float2 U1b = cmul(U1, make_float2(RS2, RS2));        // U1 * e^{+i pi/4}

#pragma unroll
    for (int k = 0; k < 8; k += 2) {
        float2 u = r[k];
        float2 v = cmul(r[k + 1], U4);
        r[k] = cadd(u, v);
        r[k + 1] = csub(u, v);
    }
#pragma unroll
    for (int k0 = 0; k0 < 8; k0 += 4) {
#pragma unroll
        for (int kk = 0; kk < 2; ++kk) {
            const int k = k0 + kk;
            float2 u = r[k];
            float2 v = cmul(r[k + 2], kk ? mpos_i(U2) : U2);
            r[k] = cadd(u, v);
            r[k + 2] = csub(u, v);
        }
    }
#pragma unroll
    for (int k = 0; k < 4; ++k) {
        float2 tw = (k == 0) ? U1 : (k == 1) ? U1b : (k == 2) ? mpos_i(U1) : mpos_i(U1b);
        float2 u = r[k];
        float2 v = cmul(r[k + 4], tw);
        r[k] = cadd(u, v);
        r[k + 4] = csub(u, v);
    }
    if (STORE) {
#pragma unroll
        for (int k = 0; k < 8; ++k) a[pass_addr<B>(sb, k)] = r[k];
    }
}

// Z1 = W_k, Z2 = W_{16384-k} of combined x+i*f spectrum -> Yhat_k = Xhat_k*Fhat_k*scale.
__device__ __forceinline__ float2 pw(float2 z1, float2 z2, float scale) {
    float2 X = make_float2(0.5f * (z1.x + z2.x), 0.5f * (z1.y - z2.y));
    float2 D = make_float2(z1.x - z2.x, z1.y + z2.y);
    float2 F = make_float2(0.5f * D.y, -0.5f * D.x);
    float2 Y = cmul(X, F);
    return make_float2(Y.x * scale, Y.y * scale);
}

// irfft pack: G = (P + conj Q) + i*E*(P - conj Q)
__device__ __forceinline__ float2 gpack(float2 P, float2 Q, float2 E) {
    float2 S  = make_float2(P.x + Q.x, P.y - Q.y);
    float2 Dd = make_float2(P.x - Q.x, P.y + Q.y);
    float2 iE = make_float2(-E.y, E.x);
    return cadd(S, cmul(iE, Dd));
}

__global__ void __launch_bounds__(NT)
fftconv_kernel(const float* __restrict__ x, const float* __restrict__ f,
               const int* __restrict__ pos, float* __restrict__ out) {
    __shared__ float2 A[N_FFT];                 // single 64 KiB workspace
    const int t   = threadIdx.x;
    const int cch = blockIdx.x;                 // channel b*256 + d
    const int bb  = cch >> 8;
    const size_t gbase = (size_t)cch * N_FFT;

    const float scale = 1.0f / (16384.0f * 16384.0f);  // two forward-norm 1/n factors
    const int st = swz(t);
    float2 r[8];
    float2 Godd[4];                             // G-odd carried across the even branch
    float sn, cs;

    // cos/sin(pi*k/8) for the odd-branch modulation (m = k*1024 + t)
    const float C8[8] = {1.0f, 0.92387953f, 0.70710678f, 0.38268343f,
                         0.0f, -0.38268343f, -0.70710678f, -0.92387953f};
    const float S8[8] = {0.0f, 0.38268343f, 0.70710678f, 0.92387953f,
                         1.0f, 0.92387953f, 0.70710678f, 0.38268343f};
    const float DC = 0.99999992646f;            // cos(pi/8192)
    const float DS = 3.83495188e-4f;            // sin(pi/8192)

    __sincosf(-PI_F * (float)t / 4096.0f, &sn, &cs);
    const float2 T1R = make_float2(cs, sn);     // reg-pass base twiddle (stages 12..10)

    // ==== ODD branch: load + modulate, reg-pass, 3 LDS passes -> Wo (bitrev) ====
    __sincosf(-PI_F * (float)t / 8192.0f, &sn, &cs);
    const float2 Bt = make_float2(cs, sn);
#pragma unroll
    for (int k = 0; k < 8; ++k) {
        const int m = k * NT + t;
        const float2 wq = make_float2(x[gbase + m], f[gbase + m]);
        const float2 tw = cmul(Bt, make_float2(C8[k], -S8[k]));  // e^{-i pi m/8192}
        r[k] = cmul(wq, tw);
    }
    fwd_core3(r, T1R);
#pragma unroll
    for (int k = 0; k < 8; ++k) A[st + (k << 10)] = r[k];        // == swz(k*1024+t)
    __syncthreads();
    fwd_pass<7, false>(A, t); __syncthreads();
    fwd_pass<4, false>(A, t); __syncthreads();
    fwd_pass<1, true >(A, t); __syncthreads();

    // ==== odd-pack: G odd bins (2j+1, 8191-2j) -> registers only ====
#pragma unroll
    for (int q = 0; q < 2; ++q) {
        const int j = (q << 10) | ((t & 7) << 7) | (t >> 3);     // bijective [0,2048)
        const int b = rev13(j);
        float sn2, cs2;
        __sincosf(PI_F * (float)j / 4096.0f, &sn2, &cs2);
        const float2 E  = make_float2(cs2, sn2);                 // e^{i pi 2j/8192}
        const float2 Eo = cmul(E, make_float2(DC, DS));          // e^{i pi (2j+1)/8192}
        const int na = 8191 - b;                                 // rev13(8191-j)
        float2 z1 = A[swz(b)];        // Wo[j]
        float2 z2 = A[swz(na)];       // Wo[8191-j]
        float2 z3 = A[swz(na - 1)];   // Wo[4095-j]
        float2 z4 = A[swz(b + 1)];    // Wo[4096+j]
        float2 P = pw(z1, z2, scale); // Yprod_{2j+1}
        float2 Q = pw(z3, z4, scale); // Yprod_{8191-2j}
        Godd[q * 2 + 0] = gpack(P, Q, Eo);                       // @ (b>>1)|4096
        Godd[q * 2 + 1] = gpack(Q, P, make_float2(-Eo.x, Eo.y)); // @ 8191-(b>>1)
    }
    __syncthreads();   // all Wo reads complete before overwriting A

    // ==== EVEN branch: reload x,f (L3-hot), reg-pass, 3 LDS passes -> We ====
#pragma unroll
    for (int k = 0; k < 8; ++k) {
        const int m = k * NT + t;
        r[k] = make_float2(x[gbase + m], f[gbase + m]);
    }
    fwd_core3(r, T1R);
#pragma unroll
    for (int k = 0; k < 8; ++k) A[st + (k << 10)] = r[k];
    __syncthreads();
    fwd_pass<7, false>(A, t); __syncthreads();
    fwd_pass<4, false>(A, t); __syncthreads();
    fwd_pass<1, true >(A, t); __syncthreads();

    // ==== even-pack: G even bins (2j, 8192-2j) + specials -> registers ====
    float2 Gev[4];
    int    Gea[4];
#pragma unroll
    for (int q = 0; q < 2; ++q) {
        const int j = (q << 10) | ((t & 7) << 7) | (t >> 3);
        const int b = rev13(j);
        float sn2, cs2;
        __sincosf(PI_F * (float)j / 4096.0f, &sn2, &cs2);
        const float2 E = make_float2(cs2, sn2);                  // e^{i pi 2j/8192}
        if (j == 0) {
            // specials: G_0 (from Ye[0], Ye[4096]) and G_4096 (= 2 conj(Ye[2048]))
            float2 a0 = A[swz(0)], a1 = A[swz(1)], a2 = A[swz(2)], a3 = A[swz(3)];
            float2 P0 = pw(a0, a0, scale);     // Ye[0]
            float2 Q0 = pw(a1, a1, scale);     // Ye[4096]
            float2 P2 = pw(a2, a3, scale);     // Ye[2048]
            Gev[0] = gpack(P0, Q0, make_float2(1.0f, 0.0f)); Gea[0] = 0;   // rev13(0)
            Gev[1] = make_float2(2.0f * P2.x, -2.0f * P2.y); Gea[1] = 1;   // rev13(4096)
        } else {
            const int c = rev13(4096 - j);
            float2 z1 = A[swz(b)];       // We[j]
            float2 z2 = A[swz(c + 1)];   // We[8192-j]
            float2 z3 = A[swz(c)];       // We[4096-j]
            float2 z4 = A[swz(b + 1)];   // We[4096+j]
            float2 P = pw(z1, z2, scale);                        // Yprod_{2j}
            float2 Q = pw(z3, z4, scale);                        // Yprod_{8192-2j}
            Gev[q * 2 + 0] = gpack(P, Q, E);                      Gea[q * 2 + 0] = b >> 1;
            Gev[q * 2 + 1] = gpack(Q, P, make_float2(-E.x, E.y)); Gea[q * 2 + 1] = c >> 1;
        }
    }
    __syncthreads();   // all We reads complete before overwriting A with G

    // ==== write Ghat (even from regs, odd from carried regs; bijective) ====
#pragma unroll
    for (int u = 0; u < 4; ++u) A[swz(Gea[u])] = Gev[u];
#pragma unroll
    for (int q = 0; q < 2; ++q) {
        const int j = (q << 10) | ((t & 7) << 7) | (t >> 3);
        const int b = rev13(j);
        A[swz((b >> 1) | 4096)]  = Godd[q * 2 + 0];
        A[swz(8191 - (b >> 1))]  = Godd[q * 2 + 1];
    }
    __syncthreads();

    // ==== inverse: c = IDFT_8192(Ghat), c_j = y_{2j} + i y_{2j+1} ====
    inv_pass<1,  true,  true >(A, t, r); __syncthreads();
    inv_pass<4,  false, true >(A, t, r); __syncthreads();
    inv_pass<7,  false, true >(A, t, r); __syncthreads();
    inv_pass<10, false, false>(A, t, r);

    // ==== store first half (j < 4096 <=> m < 8192), masked, coalesced float2 ====
    {
        float2* out2 = (float2*)out + (size_t)cch * 4096;
        const int2* pos2 = (const int2*)(pos) + (size_t)bb * 4096;
#pragma unroll
        for (int k = 0; k < 4; ++k) {
            const int j = k * NT + t;            // r[k] = c at index k*1024 + t
            const int2 pp = pos2[j];
            const float2 v = r[k];
            out2[j] = make_float2(pp.x != -1 ? v.x : 0.0f,
                                  pp.y != -1 ? v.y : 0.0f);
        }
    }
}

extern "C" void kernel_launch(void* const* d_in, const int* in_sizes, int n_in,
                              void* d_out, int out_size, void* d_ws, size_t ws_size,
                              hipStream_t stream) {
    const float* x   = (const float*)d_in[0];
    const float* f   = (const float*)d_in[1];
    const int*   pos = (const int*)d_in[2];
    float*       out = (float*)d_out;
    (void)in_sizes; (void)n_in; (void)out_size; (void)d_ws; (void)ws_size;

    // B*D = 8*256 = 2048 channels, one block each
    fftconv_kernel<<<2048, NT, 0, stream>>>(x, f, pos, out);
}

// Round 9
// 300.609 us; speedup vs baseline: 1.4035x; 1.4035x over previous
//
#include <hip/hip_runtime.h>

// FFT long conv: out[b,d,l] = (1/16384^2 forward-norm pair) * linear conv of x,f, masked.
// One workgroup per (b,d) channel; 3 complex FFTs (2 fwd + 1 packed inverse) in 64KB LDS.
//
// R9 (resubmit -- R8 bench was an infra failure, "container failed twice"; kernel
// re-audited for hangs/OOB: barriers uniform, LDS/global indices bounded, pack-round
// disjointness proven. Source unchanged to keep the measurement uncounfounded.)
//
// R9: 512-thread blocks + spill-free single-buffer structure -> 2 co-resident blocks/CU.
//  * Occupancy evidence across rounds: ALL 1024-thread configs pin at ~44% (1 block/CU,
//    even clean 40-VGPR/64KB ones, R5). R4's 512-thread blocks read ~44% = ~1.75 blocks
//    co-resident (slow only due to its spills). 512t gives two independent 8-wave
//    barrier domains per CU -> one block's barrier drain hides under the other.
//  * R8's spill source (even-pack register pile-up) is deleted via an IN-PLACE 2-round
//    even-pack: even-bin G addrs all <4096; j-even clusters read only <4096, j-odd only
//    >=4096. Round1(j even): read, barrier, write [0,2048). Round2(j odd): read >=4096,
//    write [2048,4096), no barrier needed (disjoint). Transient = 4 float2.
//  * Godd[8] (16 VGPR) is the only cross-phase state (G-odd addrs all >=4096, written
//    after the pack barrier). Peak live ~46 regs. WRITE_SIZE==65536KB is the tripwire.
//  * Two radix-8 groups per thread per pass (g=t, g=t+512), r[8] reused sequentially.
//    Group-2 twiddles = group-1 x constant (lo identical for B<=7); LDS base +512.
//
// positions arrives as int32 from the harness (int64 in the npz) - keep const int*.

#define N_FFT 8192
#define NT    512
#define PI_F  3.14159265358979323846f
#define RS2   0.70710678118654752440f

__device__ __forceinline__ float2 cmul(float2 a, float2 b) {
    return make_float2(a.x * b.x - a.y * b.y, a.x * b.y + a.y * b.x);
}
__device__ __forceinline__ float2 cadd(float2 a, float2 b) { return make_float2(a.x + b.x, a.y + b.y); }
__device__ __forceinline__ float2 csub(float2 a, float2 b) { return make_float2(a.x - b.x, a.y - b.y); }
__device__ __forceinline__ float2 mneg_i(float2 a) { return make_float2(a.y, -a.x); }  // a * (-i)
__device__ __forceinline__ float2 mpos_i(float2 a) { return make_float2(-a.y, a.x); }  // a * (+i)

__device__ __forceinline__ int rev13(int v) { return (int)(__brev((unsigned)v) >> 19); }
// LDS bank swizzle: XOR bits 1..3 with bits 4..6 (float2 units). Bijective within [0,8192).
__device__ __forceinline__ int swz(int i) { return i ^ (((i >> 4) & 7) << 1); }

// Pass ownership: group g (in [0,1024)) owns elements base + (k<<B), k=0..7 (R6, verified).
template <int B>
__device__ __forceinline__ int pass_base(int g) {
    const int lo   = g & ((1 << B) - 1);
    const int hi   = g >> B;
    const int base = (hi << (B + 3)) | lo;
    if constexpr (B == 4) return base;
    else                  return base ^ (((base >> 4) & 7) << 1);
}
template <int B>
__device__ __forceinline__ int pass_addr(int sb, int k) {
    if constexpr (B >= 7)      return sb + (k << B);
    else if constexpr (B == 4) return (sb ^ (k << 1)) + (k << 4);
    else                       return sb ^ (k << 1);
}

// ---- register-only 3-stage DIF core (stages b+2,b+1,b on r[8]); verified ----
__device__ __forceinline__ void fwd_core3(float2 r[8], float2 T1) {
    const float2 T2  = cmul(T1, T1);
    const float2 T4  = cmul(T2, T2);
    const float2 T1b = cmul(T1, make_float2(RS2, -RS2));       // T1 * e^{-i pi/4}
#pragma unroll
    for (int k = 0; k < 4; ++k) {
        float2 u = r[k], v = r[k + 4];
        r[k] = cadd(u, v);
        float2 d  = csub(u, v);
        float2 tw = (k == 0) ? T1 : (k == 1) ? T1b : (k == 2) ? mneg_i(T1) : mneg_i(T1b);
        r[k + 4] = cmul(d, tw);
    }
#pragma unroll
    for (int k0 = 0; k0 < 8; k0 += 4) {
#pragma unroll
        for (int kk = 0; kk < 2; ++kk) {
            const int k = k0 + kk;
            float2 u = r[k], v = r[k + 2];
            r[k] = cadd(u, v);
            r[k + 2] = cmul(csub(u, v), kk ? mneg_i(T2) : T2);
        }
    }
#pragma unroll
    for (int k = 0; k < 8; k += 2) {
        float2 u = r[k], v = r[k + 1];
        r[k] = cadd(u, v);
        r[k + 1] = cmul(csub(u, v), T4);
    }
}

// ---- forward DIF merged LDS pass for one group (R6 verbatim, verified) ----
template <int B, bool LAST>
__device__ __forceinline__ void fwd_pass(float2* a, int g) {
    const int h  = 1 << B;
    const int lo = g & (h - 1);
    const int sb = pass_base<B>(g);
    float2 r[8];
#pragma unroll
    for (int k = 0; k < 8; ++k) r[k] = a[pass_addr<B>(sb, k)];

    float sn, cs;
    __sincosf(-PI_F * (float)lo / (float)(4 * h), &sn, &cs);
    fwd_core3(r, make_float2(cs, sn));

    if (LAST) {  // stage 0 (half=1, twiddle 1): partner group g^1 = lane^1, same k
        const float sgn = (g & 1) ? -1.0f : 1.0f;
#pragma unroll
        for (int k = 0; k < 8; ++k) {
            float ox = __shfl_xor(r[k].x, 1);
            float oy = __shfl_xor(r[k].y, 1);
            r[k].x = ox + sgn * r[k].x;
            r[k].y = oy + sgn * r[k].y;
        }
    }
#pragma unroll
    for (int k = 0; k < 8; ++k) a[pass_addr<B>(sb, k)] = r[k];
}

// ---- inverse DIT merged LDS pass for one group (R6 verbatim, verified) ----
template <int B, bool FIRST, bool STORE>
__device__ __forceinline__ void inv_pass(float2* a, int g, float2 r[8]) {
    const int h  = 1 << B;
    const int lo = g & (h - 1);
    const int sb = pass_base<B>(g);
#pragma unroll
    for (int k = 0; k < 8; ++k) r[k] = a[pass_addr<B>(sb, k)];

    if (FIRST) {
        const float sgn = (g & 1) ? -1.0f : 1.0f;
#pragma unroll
        for (int k = 0; k < 8; ++k) {
            float ox = __shfl_xor(r[k].x, 1);
            float oy = __shfl_xor(r[k].y, 1);
            r[k].x = ox + sgn * r[k].x;
            r[k].y = oy + sgn * r[k].y;
        }
    }
    float sn, cs;
    __sincosf(PI_F * (float)lo / (float)(4 * h), &sn, &cs);
    const float2 U1  = make_float2(cs, sn);
    const float2 U2  = cmul(U1, U1);
    const float2 U4  = cmul(U2, U2);
    const float2 U1b = cmul(U1, make_float2(RS2, RS2));        // U1 * e^{+i pi/4}

#pragma unroll
    for (int k = 0; k < 8; k += 2) {
        float2 u = r[k];
        float2 v = cmul(r[k + 1], U4);
        r[k] = cadd(u, v);
        r[k + 1] = csub(u, v);
    }
#pragma unroll
    for (int k0 = 0; k0 < 8; k0 += 4) {
#pragma unroll
        for (int kk = 0; kk < 2; ++kk) {
            const int k = k0 + kk;
            float2 u = r[k];
            float2 v = cmul(r[k + 2], kk ? mpos_i(U2) : U2);
            r[k] = cadd(u, v);
            r[k + 2] = csub(u, v);
        }
    }
#pragma unroll
    for (int k = 0; k < 4; ++k) {
        float2 tw = (k == 0) ? U1 : (k == 1) ? U1b : (k == 2) ? mpos_i(U1) : mpos_i(U1b);
        float2 u = r[k];
        float2 v = cmul(r[k + 4], tw);
        r[k] = cadd(u, v);
        r[k + 4] = csub(u, v);
    }
    if (STORE) {
#pragma unroll
        for (int k = 0; k < 8; ++k) a[pass_addr<B>(sb, k)] = r[k];
    }
}

// Z1 = W_k, Z2 = W_{16384-k} of combined x+i*f spectrum -> Yhat_k = Xhat_k*Fhat_k*scale.
__device__ __forceinline__ float2 pw(float2 z1, float2 z2, float scale) {
    float2 X = make_float2(0.5f * (z1.x + z2.x), 0.5f * (z1.y - z2.y));
    float2 D = make_float2(z1.x - z2.x, z1.y + z2.y);
    float2 F = make_float2(0.5f * D.y, -0.5f * D.x);
    float2 Y = cmul(X, F);
    return make_float2(Y.x * scale, Y.y * scale);
}

// irfft pack: G = (P + conj Q) + i*E*(P - conj Q)
__device__ __forceinline__ float2 gpack(float2 P, float2 Q, float2 E) {
    float2 S  = make_float2(P.x + Q.x, P.y - Q.y);
    float2 Dd = make_float2(P.x - Q.x, P.y + Q.y);
    float2 iE = make_float2(-E.y, E.x);
    return cadd(S, cmul(iE, Dd));
}

__global__ void __launch_bounds__(NT)
fftconv_kernel(const float* __restrict__ x, const float* __restrict__ f,
               const int* __restrict__ pos, float* __restrict__ out) {
    __shared__ float2 A[N_FFT];                 // single 64 KiB workspace
    const int t   = threadIdx.x;                // 0..511
    const int cch = blockIdx.x;                 // channel b*256 + d
    const int bb  = cch >> 8;
    const size_t gbase = (size_t)cch * N_FFT;

    const float scale = 1.0f / (16384.0f * 16384.0f);  // two forward-norm 1/n factors
    const int st1 = swz(t);                     // staging base, group 1 (g = t)
    const int st2 = st1 + 512;                  // group 2 (g = t+512): swz(t+512)=swz(t)+512
    const int v   = ((t & 7) << 6) | (t >> 3);  // pack cluster map, bijective [0,512)
    float2 r[8];
    float2 Godd[8];                             // G-odd carried across the even branch
    float sn, cs;

    // cos/sin(pi*k/8) for the odd-branch modulation (m = k*1024 + g)
    const float C8[8] = {1.0f, 0.92387953f, 0.70710678f, 0.38268343f,
                         0.0f, -0.38268343f, -0.70710678f, -0.92387953f};
    const float S8[8] = {0.0f, 0.38268343f, 0.70710678f, 0.92387953f,
                         1.0f, 0.92387953f, 0.70710678f, 0.38268343f};
    const float DC = 0.99999992646f;            // cos(pi/8192)
    const float DS = 3.83495188e-4f;            // sin(pi/8192)

    // reg-pass (stages 12..10) base twiddles: T1 = e^{-i pi g/4096}
    __sincosf(-PI_F * (float)t / 4096.0f, &sn, &cs);
    const float2 T1g1 = make_float2(cs, sn);
    const float2 T1g2 = cmul(T1g1, make_float2(0.92387953f, -0.38268343f));  // * e^{-i pi/8}

    // ==== ODD branch: load + modulate e^{-i pi m/8192}, reg-pass, 3 LDS passes ====
    __sincosf(-PI_F * (float)t / 8192.0f, &sn, &cs);
    const float2 Bt1 = make_float2(cs, sn);                                  // g = t
    const float2 Bt2 = cmul(Bt1, make_float2(0.98078528f, -0.19509032f));    // * e^{-i pi/16}
#pragma unroll
    for (int k = 0; k < 8; ++k) {
        const int m = k * 1024 + t;
        const float2 wq = make_float2(x[gbase + m], f[gbase + m]);
        r[k] = cmul(wq, cmul(Bt1, make_float2(C8[k], -S8[k])));
    }
    fwd_core3(r, T1g1);
#pragma unroll
    for (int k = 0; k < 8; ++k) A[st1 + (k << 10)] = r[k];
#pragma unroll
    for (int k = 0; k < 8; ++k) {
        const int m = k * 1024 + t + 512;
        const float2 wq = make_float2(x[gbase + m], f[gbase + m]);
        r[k] = cmul(wq, cmul(Bt2, make_float2(C8[k], -S8[k])));
    }
    fwd_core3(r, T1g2);
#pragma unroll
    for (int k = 0; k < 8; ++k) A[st2 + (k << 10)] = r[k];
    __syncthreads();
    fwd_pass<7, false>(A, t); fwd_pass<7, false>(A, t + 512); __syncthreads();
    fwd_pass<4, false>(A, t); fwd_pass<4, false>(A, t + 512); __syncthreads();
    fwd_pass<1, true >(A, t); fwd_pass<1, true >(A, t + 512); __syncthreads();

    // ==== odd-pack: G odd bins (2j+1 @ (b>>1)|4096, 8191-2j @ 8191-(b>>1)) -> regs ====
#pragma unroll
    for (int qq = 0; qq < 4; ++qq) {
        const int j = (qq << 9) | v;            // covers [0,2048) bijectively
        const int b = rev13(j);
        const int na = 8191 - b;                // rev13(8191-j)
        float2 z1 = A[swz(b)];        // Wo[j]
        float2 z2 = A[swz(na)];       // Wo[8191-j]
        float2 z3 = A[swz(na - 1)];   // Wo[4095-j]
        float2 z4 = A[swz(b + 1)];    // Wo[4096+j]
        float sn2, cs2;
        __sincosf(PI_F * (float)j / 4096.0f, &sn2, &cs2);
        const float2 Eo = cmul(make_float2(cs2, sn2), make_float2(DC, DS)); // e^{i pi(2j+1)/8192}
        float2 P = pw(z1, z2, scale); // Yprod_{2j+1}
        float2 Q = pw(z3, z4, scale); // Yprod_{8191-2j}
        Godd[qq * 2 + 0] = gpack(P, Q, Eo);
        Godd[qq * 2 + 1] = gpack(Q, P, make_float2(-Eo.x, Eo.y));
    }
    __syncthreads();   // all Wo reads complete before even staging overwrites A

    // ==== EVEN branch: reload x,f (L2-hot), reg-pass, 3 LDS passes -> We ====
#pragma unroll
    for (int k = 0; k < 8; ++k) {
        const int m = k * 1024 + t;
        r[k] = make_float2(x[gbase + m], f[gbase + m]);
    }
    fwd_core3(r, T1g1);
#pragma unroll
    for (int k = 0; k < 8; ++k) A[st1 + (k << 10)] = r[k];
#pragma unroll
    for (int k = 0; k < 8; ++k) {
        const int m = k * 1024 + t + 512;
        r[k] = make_float2(x[gbase + m], f[gbase + m]);
    }
    fwd_core3(r, T1g2);
#pragma unroll
    for (int k = 0; k < 8; ++k) A[st2 + (k << 10)] = r[k];
    __syncthreads();
    fwd_pass<7, false>(A, t); fwd_pass<7, false>(A, t + 512); __syncthreads();
    fwd_pass<4, false>(A, t); fwd_pass<4, false>(A, t + 512); __syncthreads();
    fwd_pass<1, true >(A, t); fwd_pass<1, true >(A, t + 512); __syncthreads();

    // ==== even-pack, IN-PLACE 2-round (j even reads <4096 / j odd reads >=4096) ====
    // Round 1 (j = 2u even): read 4 inputs per cluster into regs.
    float2 GE[4];
#pragma unroll
    for (int qq = 0; qq < 2; ++qq) {
        const int j = 2 * ((qq << 9) | v);      // even, covers {0,2,..,2046} twice-split
        if (j == 0) {
            // specials: G_0 (Ye[0],Ye[4096]) and G_4096 (= 2 conj(Ye[2048]))
            float2 a0 = A[swz(0)], a1 = A[swz(1)], a2 = A[swz(2)], a3 = A[swz(3)];
            float2 P0 = pw(a0, a0, scale);     // Ye[0]
            float2 Q0 = pw(a1, a1, scale);     // Ye[4096]
            float2 P2 = pw(a2, a3, scale);     // Ye[2048]
            GE[0] = gpack(P0, Q0, make_float2(1.0f, 0.0f));  // -> addr 0
            GE[1] = make_float2(2.0f * P2.x, -2.0f * P2.y);  // -> addr 1
        } else {
            const int b = rev13(j);             // < 4096 (j even)
            const int c = rev13(4096 - j);      // < 4096
            float2 z1 = A[swz(b)];       // We[j]
            float2 z2 = A[swz(c + 1)];   // We[8192-j]
            float2 z3 = A[swz(c)];       // We[4096-j]
            float2 z4 = A[swz(b + 1)];   // We[4096+j]
            float sn2, cs2;
            __sincosf(PI_F * (float)j / 4096.0f, &sn2, &cs2);
            const float2 E = make_float2(cs2, sn2);          // e^{i pi 2j/8192}
            float2 P = pw(z1, z2, scale);                    // Yprod_{2j}
            float2 Q = pw(z3, z4, scale);                    // Yprod_{8192-2j}
            GE[qq * 2 + 0] = gpack(P, Q, E);
            GE[qq * 2 + 1] = gpack(Q, P, make_float2(-E.x, E.y));
        }
    }
    __syncthreads();   // round-1 reads ([0,4096)) complete before round-1 writes ([0,2048))
    // Round 1 writes + Round 2 (reads >=4096, writes [2048,4096)): disjoint, no barrier.
#pragma unroll
    for (int qq = 0; qq < 2; ++qq) {
        const int j = 2 * ((qq << 9) | v);
        if (j == 0) {
            A[swz(0)] = GE[0];
            A[swz(1)] = GE[1];
        } else {
            const int b = rev13(j);
            const int c = rev13(4096 - j);
            A[swz(b >> 1)] = GE[qq * 2 + 0];   // rev13(2j)      in [0,2048)
            A[swz(c >> 1)] = GE[qq * 2 + 1];   // rev13(8192-2j) in [0,2048)
        }
    }
#pragma unroll
    for (int qq = 0; qq < 2; ++qq) {
        const int j = 2 * ((qq << 9) | v) + 1;  // odd, in [1,2048)
        const int b = rev13(j);                 // >= 4096
        const int c = rev13(4096 - j);          // >= 4096
        float2 z1 = A[swz(b)];       // We[j]
        float2 z2 = A[swz(c + 1)];   // We[8192-j]
        float2 z3 = A[swz(c)];       // We[4096-j]
        float2 z4 = A[swz(b + 1)];   // We[4096+j]
        float sn2, cs2;
        __sincosf(PI_F * (float)j / 4096.0f, &sn2, &cs2);
        const float2 E = make_float2(cs2, sn2);
        float2 P = pw(z1, z2, scale);
        float2 Q = pw(z3, z4, scale);
        A[swz(b >> 1)] = gpack(P, Q, E);                       // in [2048,4096)
        A[swz(c >> 1)] = gpack(Q, P, make_float2(-E.x, E.y));  // in [2048,4096)
    }
    __syncthreads();   // round-2 reads (>=4096) complete before G-odd writes (>=4096)

    // ==== write G-odd from carried regs (addresses all >= 4096) ====
#pragma unroll
    for (int qq = 0; qq < 4; ++qq) {
        const int j = (qq << 9) | v;
        const int b = rev13(j);
        A[swz((b >> 1) | 4096)] = Godd[qq * 2 + 0];
        A[swz(8191 - (b >> 1))] = Godd[qq * 2 + 1];
    }
    __syncthreads();

    // ==== inverse: c = IDFT_8192(Ghat), c_j = y_{2j} + i y_{2j+1} ====
    inv_pass<1, true,  true>(A, t, r); inv_pass<1, true,  true>(A, t + 512, r); __syncthreads();
    inv_pass<4, false, true>(A, t, r); inv_pass<4, false, true>(A, t + 512, r); __syncthreads();
    inv_pass<7, false, true>(A, t, r); inv_pass<7, false, true>(A, t + 512, r); __syncthreads();

    // final pass per group (no LDS store) + masked coalesced float2 store (j < 4096)
    {
        float2* out2 = (float2*)out + (size_t)cch * 4096;
        const int2* pos2 = (const int2*)(pos) + (size_t)bb * 4096;

        inv_pass<10, false, false>(A, t, r);
#pragma unroll
        for (int k = 0; k < 4; ++k) {
            const int j = k * 1024 + t;
            const int2 pp = pos2[j];
            out2[j] = make_float2(pp.x != -1 ? r[k].x : 0.0f,
                                  pp.y != -1 ? r[k].y : 0.0f);
        }
        inv_pass<10, false, false>(A, t + 512, r);
#pragma unroll
        for (int k = 0; k < 4; ++k) {
            const int j = k * 1024 + t + 512;
            const int2 pp = pos2[j];
            out2[j] = make_float2(pp.x != -1 ? r[k].x : 0.0f,
                                  pp.y != -1 ? r[k].y : 0.0f);
        }
    }
}

extern "C" void kernel_launch(void* const* d_in, const int* in_sizes, int n_in,
                              void* d_out, int out_size, void* d_ws, size_t ws_size,
                              hipStream_t stream) {
    const float* x   = (const float*)d_in[0];
    const float* f   = (const float*)d_in[1];
    const int*   pos = (const int*)d_in[2];
    float*       out = (float*)d_out;
    (void)in_sizes; (void)n_in; (void)out_size; (void)d_ws; (void)ws_size;

    // B*D = 8*256 = 2048 channels, one block each
    fftconv_kernel<<<2048, NT, 0, stream>>>(x, f, pos, out);
}

// Round 10
// 268.859 us; speedup vs baseline: 1.5692x; 1.1181x over previous
//
#include <hip/hip_runtime.h>

// FFT long conv: out[b,d,l] = (1/16384^2 forward-norm pair) * linear conv of x,f, masked.
// One workgroup per (b,d) channel; 3 complex FFTs (2 fwd + 1 packed inverse) in 128KB LDS.
//
// R10 = R6 (best measured: 179us kernel / 272.6us total) + register first-pass graft.
//  * R9 post-mortem: 512-thread theory dead (compiler took 128 VGPR, spilled 16B/thread,
//    occupancy FELL to 22.8%). 1024-thread R6 structure is the platform optimum so far.
//  * The one remaining verified-safe lever: compute fwd stages 12..10 in REGISTERS from
//    the global load (element set k*1024+t == the coalesced load pattern), write the
//    pass OUTPUT to A[swz(t)+(k<<10)] -- bit-identical addresses to R6's staging writes
//    (pass_base<10>(t)==swz(t)), so the LDS conflict profile is R6's known-good one.
//    Present and correct in R7/R8 (their regressions were attributed elsewhere).
//  * B-branch reloads x,f (L2-hot; R9 measured the cost: +2.5MB FETCH, negligible)
//    instead of keeping w live (R5 spill rule).
//  * Saves per FFT branch: 8 LDS reads + 8 writes (P10 round-trip) + merges the staging
//    barrier into P10's. LDS ops/thread 200 -> 168, barriers 10 -> 9.
//  * Everything else (P7/P4/P1 passes, pack, inverse, store) byte-for-byte R6.
//  * Pre-commit: neutral-or-worse with clean counters => R6/R10 is the structural
//    ceiling; declare roofline.
//
// positions arrives as int32 from the harness (int64 in the npz) - keep const int*.

#define N_FFT 8192
#define NT    1024
#define NPT   8
#define PI_F  3.14159265358979323846f
#define RS2   0.70710678118654752440f

__device__ __forceinline__ float2 cmul(float2 a, float2 b) {
    return make_float2(a.x * b.x - a.y * b.y, a.x * b.y + a.y * b.x);
}
__device__ __forceinline__ float2 cadd(float2 a, float2 b) { return make_float2(a.x + b.x, a.y + b.y); }
__device__ __forceinline__ float2 csub(float2 a, float2 b) { return make_float2(a.x - b.x, a.y - b.y); }
__device__ __forceinline__ float2 mneg_i(float2 a) { return make_float2(a.y, -a.x); }  // a * (-i)
__device__ __forceinline__ float2 mpos_i(float2 a) { return make_float2(-a.y, a.x); }  // a * (+i)

__device__ __forceinline__ int rev13(int v) { return (int)(__brev((unsigned)v) >> 19); }
// LDS bank swizzle: XOR bits 1..3 with bits 4..6 (float2 units). Bijective within [0,8192).
__device__ __forceinline__ int swz(int i) { return i ^ (((i >> 4) & 7) << 1); }

// Pass ownership: thread t owns elements base + (k<<B), k=0..7 (R6, verified).
template <int B>
__device__ __forceinline__ int pass_base(int t) {
    const int lo   = t & ((1 << B) - 1);
    const int hi   = t >> B;
    const int base = (hi << (B + 3)) | lo;
    if constexpr (B == 4) return base;
    else                  return base ^ (((base >> 4) & 7) << 1);
}
template <int B>
__device__ __forceinline__ int pass_addr(int sb, int k) {
    if constexpr (B >= 7)      return sb + (k << B);
    else if constexpr (B == 4) return (sb ^ (k << 1)) + (k << 4);
    else                       return sb ^ (k << 1);
}

// ---- register-only 3-stage DIF core (stages b+2,b+1,b on r[8]); verified ----
__device__ __forceinline__ void fwd_core3(float2 r[8], float2 T1) {
    const float2 T2  = cmul(T1, T1);
    const float2 T4  = cmul(T2, T2);
    const float2 T1b = cmul(T1, make_float2(RS2, -RS2));       // T1 * e^{-i pi/4}
#pragma unroll
    for (int k = 0; k < 4; ++k) {
        float2 u = r[k], v = r[k + 4];
        r[k] = cadd(u, v);
        float2 d  = csub(u, v);
        float2 tw = (k == 0) ? T1 : (k == 1) ? T1b : (k == 2) ? mneg_i(T1) : mneg_i(T1b);
        r[k + 4] = cmul(d, tw);
    }
#pragma unroll
    for (int k0 = 0; k0 < 8; k0 += 4) {
#pragma unroll
        for (int kk = 0; kk < 2; ++kk) {
            const int k = k0 + kk;
            float2 u = r[k], v = r[k + 2];
            r[k] = cadd(u, v);
            r[k + 2] = cmul(csub(u, v), kk ? mneg_i(T2) : T2);
        }
    }
#pragma unroll
    for (int k = 0; k < 8; k += 2) {
        float2 u = r[k], v = r[k + 1];
        r[k] = cadd(u, v);
        r[k + 1] = cmul(csub(u, v), T4);
    }
}

// ---- forward DIF merged LDS pass (R6 verbatim, verified) ----
template <int B, bool LAST>
__device__ __forceinline__ void fwd_pass(float2* a, int t) {
    const int h  = 1 << B;
    const int lo = t & (h - 1);
    const int sb = pass_base<B>(t);
    float2 r[8];
#pragma unroll
    for (int k = 0; k < 8; ++k) r[k] = a[pass_addr<B>(sb, k)];

    float sn, cs;
    __sincosf(-PI_F * (float)lo / (float)(4 * h), &sn, &cs);
    fwd_core3(r, make_float2(cs, sn));

    if (LAST) {  // stage 0 (half=1, twiddle 1): partner is lane t^1, same k
        const float sgn = (t & 1) ? -1.0f : 1.0f;
#pragma unroll
        for (int k = 0; k < 8; ++k) {
            float ox = __shfl_xor(r[k].x, 1);
            float oy = __shfl_xor(r[k].y, 1);
            r[k].x = ox + sgn * r[k].x;
            r[k].y = oy + sgn * r[k].y;
        }
    }
#pragma unroll
    for (int k = 0; k < 8; ++k) a[pass_addr<B>(sb, k)] = r[k];
}

// ---- inverse DIT merged LDS pass (R6 verbatim, verified) ----
template <int B, bool FIRST, bool STORE>
__device__ __forceinline__ void inv_pass(float2* a, int t, float2 r[8]) {
    const int h  = 1 << B;
    const int lo = t & (h - 1);
    const int sb = pass_base<B>(t);
#pragma unroll
    for (int k = 0; k < 8; ++k) r[k] = a[pass_addr<B>(sb, k)];

    if (FIRST) {
        const float sgn = (t & 1) ? -1.0f : 1.0f;
#pragma unroll
        for (int k = 0; k < 8; ++k) {
            float ox = __shfl_xor(r[k].x, 1);
            float oy = __shfl_xor(r[k].y, 1);
            r[k].x = ox + sgn * r[k].x;
            r[k].y = oy + sgn * r[k].y;
        }
    }
    float sn, cs;
    __sincosf(PI_F * (float)lo / (float)(4 * h), &sn, &cs);
    const float2 U1  = make_float2(cs, sn);
    const float2 U2  = cmul(U1, U1);
    const float2 U4  = cmul(U2, U2);
    const float2 U1b = cmul(U1, make_float2(RS2, RS2));        // U1 * e^{+i pi/4}

#pragma unroll
    for (int k = 0; k < 8; k += 2) {
        float2 u = r[k];
        float2 v = cmul(r[k + 1], U4);
        r[k] = cadd(u, v);
        r[k + 1] = csub(u, v);
    }
#pragma unroll
    for (int k0 = 0; k0 < 8; k0 += 4) {
#pragma unroll
        for (int kk = 0; kk < 2; ++kk) {
            const int k = k0 + kk;
            float2 u = r[k];
            float2 v = cmul(r[k + 2], kk ? mpos_i(U2) : U2);
            r[k] = cadd(u, v);
            r[k + 2] = csub(u, v);
        }
    }
#pragma unroll
    for (int k = 0; k < 4; ++k) {
        float2 tw = (k == 0) ? U1 : (k == 1) ? U1b : (k == 2) ? mpos_i(U1) : mpos_i(U1b);
        float2 u = r[k];
        float2 v = cmul(r[k + 4], tw);
        r[k] = cadd(u, v);
        r[k + 4] = csub(u, v);
    }
    if (STORE) {
#pragma unroll
        for (int k = 0; k < 8; ++k) a[pass_addr<B>(sb, k)] = r[k];
    }
}

// Z1 = W_k, Z2 = W_{16384-k} of combined x+i*f spectrum -> Yhat_k = Xhat_k*Fhat_k*scale.
__device__ __forceinline__ float2 pw(float2 z1, float2 z2, float scale) {
    float2 X = make_float2(0.5f * (z1.x + z2.x), 0.5f * (z1.y - z2.y));
    float2 D = make_float2(z1.x - z2.x, z1.y + z2.y);
    float2 F = make_float2(0.5f * D.y, -0.5f * D.x);
    float2 Y = cmul(X, F);
    return make_float2(Y.x * scale, Y.y * scale);
}

// irfft pack: G = (P + conj Q) + i*E*(P - conj Q)
__device__ __forceinline__ float2 gpack(float2 P, float2 Q, float2 E) {
    float2 S  = make_float2(P.x + Q.x, P.y - Q.y);
    float2 Dd = make_float2(P.x - Q.x, P.y + Q.y);
    float2 iE = make_float2(-E.y, E.x);
    return cadd(S, cmul(iE, Dd));
}

__global__ void __launch_bounds__(NT)
fftconv_kernel(const float* __restrict__ x, const float* __restrict__ f,
               const int* __restrict__ pos, float* __restrict__ out) {
    __shared__ float2 A[N_FFT];                 // We spectrum / G / inverse workspace
    __shared__ float2 Bb[N_FFT];                // Wo spectrum
    const int t   = threadIdx.x;
    const int cch = blockIdx.x;                 // channel b*256 + d
    const int bb  = cch >> 8;
    const size_t gbase = (size_t)cch * N_FFT;

    const float scale = 1.0f / (16384.0f * 16384.0f);  // two forward-norm 1/n factors
    const int st = swz(t);                      // == pass_base<10>(t)
    float2 r[8];
    float sn, cs;

    // cos/sin(pi*k/8) for the odd-branch modulation (m = k*1024 + t)
    const float C8[8] = {1.0f, 0.92387953f, 0.70710678f, 0.38268343f,
                         0.0f, -0.38268343f, -0.70710678f, -0.92387953f};
    const float S8[8] = {0.0f, 0.38268343f, 0.70710678f, 0.92387953f,
                         1.0f, 0.92387953f, 0.70710678f, 0.38268343f};

    // reg first-pass base twiddle (stages 12..10): T1 = e^{-i pi t/4096}
    __sincosf(-PI_F * (float)t / 4096.0f, &sn, &cs);
    const float2 T1R = make_float2(cs, sn);

    // ==== A branch: load w = x + i f, fwd stages 12..10 in regs, write pass output ====
#pragma unroll
    for (int k = 0; k < 8; ++k) {
        const int m = k * NT + t;
        r[k] = make_float2(x[gbase + m], f[gbase + m]);
    }
    fwd_core3(r, T1R);
#pragma unroll
    for (int k = 0; k < 8; ++k) A[st + (k << 10)] = r[k];   // == pass_addr<10>(st,k)

    // ==== B branch: reload (L2-hot) + modulate e^{-i pi m/8192}, same reg pass ====
    __sincosf(-PI_F * (float)t / 8192.0f, &sn, &cs);
    const float2 Bt = make_float2(cs, sn);
#pragma unroll
    for (int k = 0; k < 8; ++k) {
        const int m = k * NT + t;
        const float2 wq = make_float2(x[gbase + m], f[gbase + m]);
        r[k] = cmul(wq, cmul(Bt, make_float2(C8[k], -S8[k])));
    }
    fwd_core3(r, T1R);
#pragma unroll
    for (int k = 0; k < 8; ++k) Bb[st + (k << 10)] = r[k];
    __syncthreads();

    // ==== remaining forward passes (shared barriers): stages 9..0 ====
    fwd_pass<7, false>(A, t); fwd_pass<7, false>(Bb, t); __syncthreads();
    fwd_pass<4, false>(A, t); fwd_pass<4, false>(Bb, t); __syncthreads();
    fwd_pass<1, true >(A, t); fwd_pass<1, true >(Bb, t); __syncthreads();

    // ==== pointwise + irfft pack: build Ghat (bitrev) into A (R6 verbatim) ====
    {
        float2 Gv[8];
        int    Ga[8];
        const float DC = 0.99999992646f;        // cos(pi/8192)
        const float DS = 3.83495188e-4f;        // sin(pi/8192)
#pragma unroll
        for (int q = 0; q < 2; ++q) {
            const int j = (q << 10) | ((t & 7) << 7) | (t >> 3);   // bijective [0,2048)
            const int b = rev13(j);
            float sn2, cs2;
            __sincosf(PI_F * (float)j / 4096.0f, &sn2, &cs2);
            const float2 E  = make_float2(cs2, sn2);               // e^{i pi 2j/8192}
            const float2 Eo = cmul(E, make_float2(DC, DS));        // e^{i pi (2j+1)/8192}

            if (j == 0) {
                // specials: G_0 (from Ye[0], Ye[4096]) and G_4096 (= 2 conj(Ye[2048]))
                float2 a0 = A[swz(0)], a1 = A[swz(1)], a2 = A[swz(2)], a3 = A[swz(3)];
                float2 P0 = pw(a0, a0, scale);     // Ye[0]
                float2 Q0 = pw(a1, a1, scale);     // Ye[4096]
                float2 P2 = pw(a2, a3, scale);     // Ye[2048]
                Gv[0] = gpack(P0, Q0, make_float2(1.0f, 0.0f)); Ga[0] = 0;   // rev13(0)
                Gv[1] = make_float2(2.0f * P2.x, -2.0f * P2.y); Ga[1] = 1;   // rev13(4096)
            } else {
                const int c = rev13(4096 - j);
                float2 z1 = A[swz(b)];       // We[j]
                float2 z2 = A[swz(c + 1)];   // We[8192-j]
                float2 z3 = A[swz(c)];       // We[4096-j]
                float2 z4 = A[swz(b + 1)];   // We[4096+j]
                float2 P = pw(z1, z2, scale);                    // Yprod_{2j}
                float2 Q = pw(z3, z4, scale);                    // Yprod_{8192-2j}
                Gv[q * 4 + 0] = gpack(P, Q, E);                       Ga[q * 4 + 0] = b >> 1;
                Gv[q * 4 + 1] = gpack(Q, P, make_float2(-E.x, E.y));  Ga[q * 4 + 1] = c >> 1;
            }
            {   // odd bins 2j+1 and 8191-2j (no specials)
                const int na = 8191 - b;      // rev13(8191-j)
                float2 z1 = Bb[swz(b)];       // Wo[j]
                float2 z2 = Bb[swz(na)];      // Wo[8191-j]
                float2 z3 = Bb[swz(na - 1)];  // Wo[4095-j]
                float2 z4 = Bb[swz(b + 1)];   // Wo[4096+j]
                float2 P = pw(z1, z2, scale);                    // Yprod_{2j+1}
                float2 Q = pw(z3, z4, scale);                    // Yprod_{8191-2j}
                Gv[q * 4 + 2] = gpack(P, Q, Eo);                        Ga[q * 4 + 2] = (b >> 1) | 4096;
                Gv[q * 4 + 3] = gpack(Q, P, make_float2(-Eo.x, Eo.y));  Ga[q * 4 + 3] = 8191 - (b >> 1);
            }
        }
        __syncthreads();   // all We/Wo reads complete before overwriting A with G
#pragma unroll
        for (int u = 0; u < 8; ++u) A[swz(Ga[u])] = Gv[u];
    }
    __syncthreads();

    // ==== inverse: c = IDFT_8192(Ghat), c_j = y_{2j} + i y_{2j+1} (R6 verbatim) ====
    inv_pass<1,  true,  true >(A, t, r); __syncthreads();
    inv_pass<4,  false, true >(A, t, r); __syncthreads();
    inv_pass<7,  false, true >(A, t, r); __syncthreads();
    inv_pass<10, false, false>(A, t, r);

    // ==== store first half (j < 4096 <=> m < 8192), masked, coalesced float2 ====
    {
        float2* out2 = (float2*)out + (size_t)cch * 4096;
        const int2* pos2 = (const int2*)(pos) + (size_t)bb * 4096;
#pragma unroll
        for (int k = 0; k < 4; ++k) {
            const int j = k * NT + t;            // r[k] = c at index k*1024 + t
            const int2 pp = pos2[j];
            const float2 v = r[k];
            out2[j] = make_float2(pp.x != -1 ? v.x : 0.0f,
                                  pp.y != -1 ? v.y : 0.0f);
        }
    }
}

extern "C" void kernel_launch(void* const* d_in, const int* in_sizes, int n_in,
                              void* d_out, int out_size, void* d_ws, size_t ws_size,
                              hipStream_t stream) {
    const float* x   = (const float*)d_in[0];
    const float* f   = (const float*)d_in[1];
    const int*   pos = (const int*)d_in[2];
    float*       out = (float*)d_out;
    (void)in_sizes; (void)n_in; (void)out_size; (void)d_ws; (void)ws_size;

    // B*D = 8*256 = 2048 channels, one block each
    fftconv_kernel<<<2048, NT, 0, stream>>>(x, f, pos, out);
}